// Round 6
// baseline (106.414 us; speedup 1.0000x reference)
//
#include <hip/hip_runtime.h>

#define HW 28
#define NPIX 784
#define NB 512
#define PR 34                    // padded rows: -3..30
#define PC 52                    // padded row stride in halfs (104 B): 16-row b64 reads conflict-free
#define PLANE (PR * PC)          // 1768 halfs per plane

typedef _Float16 half8 __attribute__((ext_vector_type(8)));
typedef float    f32x4 __attribute__((ext_vector_type(4)));

union H8 { unsigned short s[8]; uint2 u2[2]; half8 h; };

// ---------------------------------------------------------------------------
// r22: MFMA conv. r0-r5 evidence: conv dot2s cost 44k VALU-cyc/SIMD at
// 2cyc/MAC and nothing schedules around them. Reformulate: 7x7 correlation =
// sum over di of banded Toeplitz matmuls -> mfma_f32_16x16x32_f16.
//   A[m][k]  = plane[rt+di+m][ct+k]          (m=lane&15, k-slots (lane>>4)*4+j / +16)
//   B[k][n]  = w[di][k-n] (0<=k-n<=6 else 0) (n=lane&15, same k-slot map -> perm cancels)
//   C/D      = col=lane&15, row=(lane>>4)*4+reg   [m89-verified]
// num += ev*B(qw) + pv*B(ew); den += ev*B(ew). 84 MFMA/stage/wave vs 5488
// cyc of dot2. B read per-lane from zero-padded LDS tables (48 halfs/di):
// band zeros are EXACT zeros, A garbage cols are finite 0x3C00 -> 0*finite=0.
// ---------------------------------------------------------------------------
__device__ __forceinline__ void mconv(const _Float16 (*ev)[PC],
                                      const _Float16 (*pv)[PC],
                                      const unsigned short (*tbl)[7][48], // [wt][di][pos]
                                      int q, int n15, f32x4 o[2][2])
{
    f32x4 num[2][2], den[2][2];
#pragma unroll
    for (int a = 0; a < 2; ++a)
#pragma unroll
        for (int c = 0; c < 2; ++c) {
            num[a][c] = (f32x4){0.f, 0.f, 0.f, 0.f};
            den[a][c] = (f32x4){0.f, 0.f, 0.f, 0.f};
        }

    const int bp = 16 + 4 * q - n15;        // table base position, in [1,28]

#pragma unroll
    for (int di = 0; di < 7; ++di) {
        H8 bq, be;
        const unsigned short* tq = &tbl[0][di][0];
        const unsigned short* te = &tbl[1][di][0];
#pragma unroll
        for (int j = 0; j < 4; ++j) {       // k-slots: 0..3 -> 4q+j, 4..7 -> 16+4q+j
            bq.s[j]     = tq[bp + j];
            bq.s[4 + j] = tq[bp + 16 + j];
            be.s[j]     = te[bp + j];
            be.s[4 + j] = te[bp + 16 + j];
        }
#pragma unroll
        for (int rt = 0; rt < 2; ++rt) {
            const int row = rt * 12 + di + n15;          // <= 33
#pragma unroll
            for (int ct = 0; ct < 2; ++ct) {
                const int col = ct * 16 + 4 * q;         // 8B-aligned (104B rows)
                H8 ea, pa;
                ea.u2[0] = *(const uint2*)&ev[row][col];
                ea.u2[1] = *(const uint2*)&ev[row][col + 16];
                pa.u2[0] = *(const uint2*)&pv[row][col];
                pa.u2[1] = *(const uint2*)&pv[row][col + 16];
                num[rt][ct] = __builtin_amdgcn_mfma_f32_16x16x32_f16(ea.h, bq.h, num[rt][ct], 0, 0, 0);
                num[rt][ct] = __builtin_amdgcn_mfma_f32_16x16x32_f16(pa.h, be.h, num[rt][ct], 0, 0, 0);
                den[rt][ct] = __builtin_amdgcn_mfma_f32_16x16x32_f16(ea.h, be.h, den[rt][ct], 0, 0, 0);
            }
        }
    }
#pragma unroll
    for (int a = 0; a < 2; ++a)
#pragma unroll
        for (int c = 0; c < 2; ++c)
#pragma unroll
            for (int v = 0; v < 4; ++v)
                o[a][c][v] = num[a][c][v] * __builtin_amdgcn_rcpf(den[a][c][v]);
}

__device__ __forceinline__ float sigmoidf_(float s) {
    return __builtin_amdgcn_rcpf(1.f + __expf(-s));
}

// ---------------------------------------------------------------------------
// FULLY FUSED, 8 waves/block, ONE BRANCH PER WAVE, one block per image.
// LDS: planes 56,576 + wtbl 10,752 + mlp 2,560 = 69,888 B -> 2 blocks/CU.
// __launch_bounds__(512,2) -> VGPR cap 128 (live ~100, must not spill).
// No barriers until feat: planes/tables are wave-local per branch.
// ---------------------------------------------------------------------------
__global__ __launch_bounds__(512, 2) void smorph_net_kernel(
    const float* __restrict__ x,       // [512,784]
    const float* __restrict__ sw,      // [8,2,49]
    const float* __restrict__ sa,      // [8,2]
    const float* __restrict__ W1, const float* __restrict__ b1,
    const float* __restrict__ W2, const float* __restrict__ b2,
    const float* __restrict__ W3, const float* __restrict__ b3,
    float* __restrict__ out)           // [512,10]
{
    __shared__ __align__(16) _Float16       planes[8][2][PR][PC];  // 56,576 B
    __shared__ __align__(16) unsigned short wtbl[8][2][7][48];     // 10,752 B
    __shared__ __align__(16) float          mlp[392 + 120 + 128];  //  2,560 B

    const int b    = blockIdx.x;
    const int tid  = threadIdx.x;
    const int f    = tid >> 6;
    const int lane = tid & 63;
    const int n15  = lane & 15;
    const int q    = lane >> 4;

    _Float16 (*ev)[PC] = planes[f][0];
    _Float16 (*pv)[PC] = planes[f][1];
    const float* src = x + (size_t)b * NPIX;

    const float a1 = sa[f * 2 + 0];
    const float a2 = sa[f * 2 + 1];

    // per-branch packed weights (qw=w*e^{aw} lo, ew=e^{aw} hi) per tap-lane
    unsigned wp1 = 0, wp2 = 0;
    if (lane < 49) {
        union { _Float16 h[2]; unsigned u; } p;
        float w1v = sw[(f * 2 + 0) * 49 + lane];
        float e1  = __expf(a1 * w1v);
        p.h[0] = (_Float16)(w1v * e1);
        p.h[1] = (_Float16)e1;
        wp1 = p.u;
        float w2v = sw[(f * 2 + 1) * 49 + lane];
        float e2  = __expf(a2 * w2v);
        p.h[0] = (_Float16)(w2v * e2);
        p.h[1] = (_Float16)e2;
        wp2 = p.u;
    }

    // zero tables (band zeros must be exact), then stage-1 weights
    {
        unsigned* tz = (unsigned*)&wtbl[f][0][0][0];   // 2*7*48/2 = 336 uints
        for (int i = lane; i < 336; i += 64) tz[i] = 0;
    }
    if (lane < 49) {
        int di = lane / 7, t = lane - di * 7;
        wtbl[f][0][di][16 + t] = (unsigned short)(wp1 & 0xFFFF);   // qw
        wtbl[f][1][di][16 + t] = (unsigned short)(wp1 >> 16);      // ew
    }

    // plane prefill: border (ev=1, pv=0) everywhere
    {
        unsigned* evu = (unsigned*)&planes[f][0][0][0];
        unsigned* pvu = (unsigned*)&planes[f][1][0][0];
        for (int i = lane; i < PLANE / 2; i += 64) {
            evu[i] = 0x3C003C00u;
            pvu[i] = 0u;
        }
    }

    // interior pack: independent unrolled loads (batched latency)
#pragma unroll
    for (int k = 0; k < 13; ++k) {
        int p = lane + 64 * k;
        if (p < NPIX) {
            float v = src[p];
            int pi = p / HW;
            int pj = p - pi * HW;
            float e = __expf(a1 * v);
            ev[pi + 3][pj + 3] = (_Float16)e;
            pv[pi + 3][pj + 3] = (_Float16)(v * e);
        }
    }

    // ---- stage 1 conv (MFMA) ----
    f32x4 o1_[2][2];
    mconv(ev, pv, wtbl[f], q, n15, o1_);

    // stage-1 -> stage-2 transition: write (ev2,pv2) planes in place.
    // lane's C elements: row = rt*12 + 4q + v, col = ct*16 + n15.
    // Skip junk cols >=28 (would clobber border cells). Dup rows 12..15
    // written twice with identical values (benign).
#pragma unroll
    for (int rt = 0; rt < 2; ++rt)
#pragma unroll
        for (int ct = 0; ct < 2; ++ct) {
            if (ct == 1 && n15 >= 12) continue;
#pragma unroll
            for (int v = 0; v < 4; ++v) {
                int row = rt * 12 + 4 * q + v;
                int col = ct * 16 + n15;
                float ov = o1_[rt][ct][v];
                float e  = __expf(a2 * ov);
                ev[row + 3][col + 3] = (_Float16)e;
                pv[row + 3][col + 3] = (_Float16)(ov * e);
            }
        }

    // stage-2 weights into tables (wave-local overwrite of band entries)
    if (lane < 49) {
        int di = lane / 7, t = lane - di * 7;
        wtbl[f][0][di][16 + t] = (unsigned short)(wp2 & 0xFFFF);
        wtbl[f][1][di][16 + t] = (unsigned short)(wp2 >> 16);
    }

    // ---- stage 2 conv (MFMA) ----
    f32x4 o2_[2][2];
    mconv(ev, pv, wtbl[f], q, n15, o2_);

    float* feat = mlp;
    float* h1   = mlp + 392;
    float* h2   = mlp + 512;

    // 4x4 mean pool straight from C-registers: lane holds a 4-row strip of
    // one pool block-row at col ct*16+n15; shfl over n15&3 sums the 4 cols.
#pragma unroll
    for (int rt = 0; rt < 2; ++rt)
#pragma unroll
        for (int ct = 0; ct < 2; ++ct) {
            float s = o2_[rt][ct][0] + o2_[rt][ct][1] + o2_[rt][ct][2] + o2_[rt][ct][3];
            s += __shfl_xor(s, 1);
            s += __shfl_xor(s, 2);
            int pr = rt ? (3 + q) : q;
            int pc = (ct ? 4 : 0) + (n15 >> 2);
            bool ok = ((n15 & 3) == 0)
                   && !(rt == 1 && q == 0)          // rows 12..15 dup of rt=0,q=3
                   && !(ct == 1 && n15 >= 12);      // junk cols 28..31
            if (ok) feat[f * 49 + pr * 7 + pc] = s * 0.0625f;
        }
    __syncthreads();

    // ---- inline MLP (4 lanes per neuron) ----
    if (tid < 480) {
        int n = tid >> 2, h = tid & 3;
        const float4* wr = (const float4*)(W1 + n * 392);
        const float4* fv = (const float4*)feat;
        float c0 = 0.f, c1 = 0.f, c2 = 0.f, c3 = 0.f;
#pragma unroll 2
        for (int k = h; k < 98; k += 4) {
            float4 w = wr[k];
            float4 v = fv[k];
            c0 = fmaf(w.x, v.x, c0);
            c1 = fmaf(w.y, v.y, c1);
            c2 = fmaf(w.z, v.z, c2);
            c3 = fmaf(w.w, v.w, c3);
        }
        float acc = (c0 + c1) + (c2 + c3);
        acc += __shfl_xor(acc, 1);
        acc += __shfl_xor(acc, 2);
        if (h == 0) h1[n] = sigmoidf_(acc + b1[n]);
    }
    __syncthreads();

    if (tid < 336) {
        int n = tid >> 2, h = tid & 3;
        const float4* wr = (const float4*)(W2 + n * 120);
        const float4* hv = (const float4*)h1;
        float c0 = 0.f, c1 = 0.f, c2 = 0.f, c3 = 0.f;
        for (int k = h; k < 30; k += 4) {
            float4 w = wr[k];
            float4 v = hv[k];
            c0 = fmaf(w.x, v.x, c0);
            c1 = fmaf(w.y, v.y, c1);
            c2 = fmaf(w.z, v.z, c2);
            c3 = fmaf(w.w, v.w, c3);
        }
        float acc = (c0 + c1) + (c2 + c3);
        acc += __shfl_xor(acc, 1);
        acc += __shfl_xor(acc, 2);
        if (h == 0) h2[n] = sigmoidf_(acc + b2[n]);
    }
    __syncthreads();

    if (tid < 40) {
        int n = tid >> 2, qh = tid & 3;
        const float4* wr = (const float4*)(W3 + n * 84);
        const float4* hv = (const float4*)h2;
        float c0 = 0.f, c1 = 0.f, c2 = 0.f, c3 = 0.f;
        for (int k = qh; k < 21; k += 4) {
            float4 w = wr[k];
            float4 v = hv[k];
            c0 = fmaf(w.x, v.x, c0);
            c1 = fmaf(w.y, v.y, c1);
            c2 = fmaf(w.z, v.z, c2);
            c3 = fmaf(w.w, v.w, c3);
        }
        float acc = (c0 + c1) + (c2 + c3);
        acc += __shfl_xor(acc, 1);
        acc += __shfl_xor(acc, 2);
        if (qh == 0) out[(size_t)b * 10 + n] = sigmoidf_(acc + b3[n]);
    }
}

extern "C" void kernel_launch(void* const* d_in, const int* in_sizes, int n_in,
                              void* d_out, int out_size, void* d_ws, size_t ws_size,
                              hipStream_t stream) {
    const float* x  = (const float*)d_in[0];
    const float* sw = (const float*)d_in[1];
    const float* sa = (const float*)d_in[2];
    const float* W1 = (const float*)d_in[3];
    const float* b1 = (const float*)d_in[4];
    const float* W2 = (const float*)d_in[5];
    const float* b2 = (const float*)d_in[6];
    const float* W3 = (const float*)d_in[7];
    const float* b3 = (const float*)d_in[8];
    float* out = (float*)d_out;

    smorph_net_kernel<<<NB, 512, 0, stream>>>(x, sw, sa, W1, b1, W2, b2, W3, b3, out);
}

// Round 7
// 102.110 us; speedup vs baseline: 1.0421x; 1.0421x over previous
//
#include <hip/hip_runtime.h>

#define HW 28
#define NPIX 784
#define NIMG 512
#define NBLK 256                 // 2 images per block
#define PR 34                    // padded rows: -3..30
#define PC 52                    // padded row stride in halfs (104 B): 16-row b64 reads conflict-free
#define PLANE (PR * PC)          // 1768 halfs per plane

typedef _Float16 half8 __attribute__((ext_vector_type(8)));
typedef float    f32x4 __attribute__((ext_vector_type(4)));

union H8 { unsigned short s[8]; uint2 u2[2]; half8 h; };

// ---------------------------------------------------------------------------
// r23: TWO IMAGES PER BLOCK, INTERLEAVED PER WAVE.
// r17-r22 evidence: six structurally different conv cores (dot2 unrolled /
// SGPR weights / prefetch / parity-split / rolled / MFMA) ALL land at
// 41-46us while VALUBusy swung 56%->15% and MfmaUtil 0->9%. Time is NOT set
// by any measured pipe. Surviving theories: (a) per-workgroup ramp cost
// (512 blocks), (b) per-block latency chain with too little ILP. This
// version halves blocks to 256 and gives each wave TWO independent images
// interleaved instruction-by-instruction: under (a) ramp halves, under (b)
// ILP doubles. B-fragments + MLP weight loads are shared across the pair.
// MFMA mapping (r22, verified): A[m][k]=plane[rt*12+di+m][ct*16+k],
// B[k][n]=w[di][k-n] zero-padded band, C/D col=lane&15 row=(lane>>4)*4+reg.
// ---------------------------------------------------------------------------
__device__ __forceinline__ void mconv2(const _Float16 (*ev0)[PC], const _Float16 (*pv0)[PC],
                                       const _Float16 (*ev1)[PC], const _Float16 (*pv1)[PC],
                                       const unsigned short (*tbl)[7][48], // [wt][di][pos]
                                       int q, int n15, f32x4 o[2][2][2])   // [img][rt][ct]
{
    f32x4 num[2][2][2], den[2][2][2];
#pragma unroll
    for (int i = 0; i < 2; ++i)
#pragma unroll
        for (int a = 0; a < 2; ++a)
#pragma unroll
            for (int c = 0; c < 2; ++c) {
                num[i][a][c] = (f32x4){0.f, 0.f, 0.f, 0.f};
                den[i][a][c] = (f32x4){0.f, 0.f, 0.f, 0.f};
            }

    const int bp = 16 + 4 * q - n15;        // table base position, in [1,28]

#pragma unroll
    for (int di = 0; di < 7; ++di) {
        // B fragments: gathered ONCE, shared by both images
        H8 bq, be;
        const unsigned short* tq = &tbl[0][di][0];
        const unsigned short* te = &tbl[1][di][0];
#pragma unroll
        for (int j = 0; j < 4; ++j) {       // k-slots: 0..3 -> 4q+j, 4..7 -> 16+4q+j
            bq.s[j]     = tq[bp + j];
            bq.s[4 + j] = tq[bp + 16 + j];
            be.s[j]     = te[bp + j];
            be.s[4 + j] = te[bp + 16 + j];
        }
#pragma unroll
        for (int rt = 0; rt < 2; ++rt) {
            const int row = rt * 12 + di + n15;          // <= 33
#pragma unroll
            for (int ct = 0; ct < 2; ++ct) {
                const int col = ct * 16 + 4 * q;         // 8B-aligned (104B rows)
                H8 ea0, pa0, ea1, pa1;
                ea0.u2[0] = *(const uint2*)&ev0[row][col];
                ea0.u2[1] = *(const uint2*)&ev0[row][col + 16];
                pa0.u2[0] = *(const uint2*)&pv0[row][col];
                pa0.u2[1] = *(const uint2*)&pv0[row][col + 16];
                ea1.u2[0] = *(const uint2*)&ev1[row][col];
                ea1.u2[1] = *(const uint2*)&ev1[row][col + 16];
                pa1.u2[0] = *(const uint2*)&pv1[row][col];
                pa1.u2[1] = *(const uint2*)&pv1[row][col + 16];
                num[0][rt][ct] = __builtin_amdgcn_mfma_f32_16x16x32_f16(ea0.h, bq.h, num[0][rt][ct], 0, 0, 0);
                num[1][rt][ct] = __builtin_amdgcn_mfma_f32_16x16x32_f16(ea1.h, bq.h, num[1][rt][ct], 0, 0, 0);
                num[0][rt][ct] = __builtin_amdgcn_mfma_f32_16x16x32_f16(pa0.h, be.h, num[0][rt][ct], 0, 0, 0);
                num[1][rt][ct] = __builtin_amdgcn_mfma_f32_16x16x32_f16(pa1.h, be.h, num[1][rt][ct], 0, 0, 0);
                den[0][rt][ct] = __builtin_amdgcn_mfma_f32_16x16x32_f16(ea0.h, be.h, den[0][rt][ct], 0, 0, 0);
                den[1][rt][ct] = __builtin_amdgcn_mfma_f32_16x16x32_f16(ea1.h, be.h, den[1][rt][ct], 0, 0, 0);
            }
        }
    }
#pragma unroll
    for (int i = 0; i < 2; ++i)
#pragma unroll
        for (int a = 0; a < 2; ++a)
#pragma unroll
            for (int c = 0; c < 2; ++c)
#pragma unroll
                for (int v = 0; v < 4; ++v)
                    o[i][a][c][v] = num[i][a][c][v] * __builtin_amdgcn_rcpf(den[i][a][c][v]);
}

__device__ __forceinline__ float sigmoidf_(float s) {
    return __builtin_amdgcn_rcpf(1.f + __expf(-s));
}

// ---------------------------------------------------------------------------
// FULLY FUSED, 8 waves/block, ONE BRANCH x TWO IMAGES PER WAVE.
// LDS: planes 113,152 + wtbl 10,752 + mlp 5,120 = 129,024 B -> 1 block/CU.
// __launch_bounds__(512,1): empirical mapping (r12: (512,4)->cap 64) gives
// cap 256 VGPR; live ~140. 256 blocks on 256 CUs.
// ---------------------------------------------------------------------------
__global__ __launch_bounds__(512, 1) void smorph_net_kernel(
    const float* __restrict__ x,       // [512,784]
    const float* __restrict__ sw,      // [8,2,49]
    const float* __restrict__ sa,      // [8,2]
    const float* __restrict__ W1, const float* __restrict__ b1,
    const float* __restrict__ W2, const float* __restrict__ b2,
    const float* __restrict__ W3, const float* __restrict__ b3,
    float* __restrict__ out)           // [512,10]
{
    __shared__ __align__(16) _Float16       planes[8][2][2][PR][PC]; // 113,152 B [branch][img][ev/pv]
    __shared__ __align__(16) unsigned short wtbl[8][2][7][48];       //  10,752 B
    __shared__ __align__(16) float          mlp2[2][640];            //   5,120 B (feat|h1|h2 per img)

    const int b0   = blockIdx.x * 2;   // image pair
    const int tid  = threadIdx.x;
    const int f    = tid >> 6;
    const int lane = tid & 63;
    const int n15  = lane & 15;
    const int q    = lane >> 4;

    _Float16 (*ev0)[PC] = planes[f][0][0];
    _Float16 (*pv0)[PC] = planes[f][0][1];
    _Float16 (*ev1)[PC] = planes[f][1][0];
    _Float16 (*pv1)[PC] = planes[f][1][1];
    const float* src0 = x + (size_t)b0 * NPIX;
    const float* src1 = src0 + NPIX;

    const float a1 = sa[f * 2 + 0];
    const float a2 = sa[f * 2 + 1];

    // per-branch packed weights (qw=w*e^{aw} lo, ew=e^{aw} hi) per tap-lane
    unsigned wp1 = 0, wp2 = 0;
    if (lane < 49) {
        union { _Float16 h[2]; unsigned u; } p;
        float w1v = sw[(f * 2 + 0) * 49 + lane];
        float e1  = __expf(a1 * w1v);
        p.h[0] = (_Float16)(w1v * e1);
        p.h[1] = (_Float16)e1;
        wp1 = p.u;
        float w2v = sw[(f * 2 + 1) * 49 + lane];
        float e2  = __expf(a2 * w2v);
        p.h[0] = (_Float16)(w2v * e2);
        p.h[1] = (_Float16)e2;
        wp2 = p.u;
    }

    // zero tables (band zeros must be exact), then stage-1 weights
    {
        unsigned* tz = (unsigned*)&wtbl[f][0][0][0];   // 336 uints
        for (int i = lane; i < 336; i += 64) tz[i] = 0;
    }
    if (lane < 49) {
        int di = lane / 7, t = lane - di * 7;
        wtbl[f][0][di][16 + t] = (unsigned short)(wp1 & 0xFFFF);   // qw
        wtbl[f][1][di][16 + t] = (unsigned short)(wp1 >> 16);      // ew
    }

    // plane prefill: border (ev=1, pv=0) everywhere, both images
    {
        unsigned* e0u = (unsigned*)&planes[f][0][0][0][0];
        unsigned* p0u = (unsigned*)&planes[f][0][1][0][0];
        unsigned* e1u = (unsigned*)&planes[f][1][0][0][0];
        unsigned* p1u = (unsigned*)&planes[f][1][1][0][0];
        for (int i = lane; i < PLANE / 2; i += 64) {
            e0u[i] = 0x3C003C00u; p0u[i] = 0u;
            e1u[i] = 0x3C003C00u; p1u[i] = 0u;
        }
    }

    // interior pack: both images interleaved; independent unrolled loads
#pragma unroll
    for (int k = 0; k < 13; ++k) {
        int p = lane + 64 * k;
        if (p < NPIX) {
            float v0 = src0[p];
            float v1 = src1[p];
            int pi = p / HW;
            int pj = p - pi * HW;
            float e0 = __expf(a1 * v0);
            float e1 = __expf(a1 * v1);
            ev0[pi + 3][pj + 3] = (_Float16)e0;
            pv0[pi + 3][pj + 3] = (_Float16)(v0 * e0);
            ev1[pi + 3][pj + 3] = (_Float16)e1;
            pv1[pi + 3][pj + 3] = (_Float16)(v1 * e1);
        }
    }

    // ---- stage 1 conv (MFMA, both images) ----
    f32x4 o1_[2][2][2];
    mconv2(ev0, pv0, ev1, pv1, wtbl[f], q, n15, o1_);

    // stage-1 -> stage-2 transition: write (ev2,pv2) planes in place.
    // lane's C elements: row = rt*12 + 4q + v, col = ct*16 + n15.
    // Skip junk cols >=28; dup rows 12..15 written twice with equal values.
#pragma unroll
    for (int rt = 0; rt < 2; ++rt)
#pragma unroll
        for (int ct = 0; ct < 2; ++ct) {
            if (ct == 1 && n15 >= 12) continue;
#pragma unroll
            for (int v = 0; v < 4; ++v) {
                int row = rt * 12 + 4 * q + v;
                int col = ct * 16 + n15;
                float ova = o1_[0][rt][ct][v];
                float ovb = o1_[1][rt][ct][v];
                float ea  = __expf(a2 * ova);
                float eb  = __expf(a2 * ovb);
                ev0[row + 3][col + 3] = (_Float16)ea;
                pv0[row + 3][col + 3] = (_Float16)(ova * ea);
                ev1[row + 3][col + 3] = (_Float16)eb;
                pv1[row + 3][col + 3] = (_Float16)(ovb * eb);
            }
        }

    // stage-2 weights into tables (wave-local overwrite of band entries)
    if (lane < 49) {
        int di = lane / 7, t = lane - di * 7;
        wtbl[f][0][di][16 + t] = (unsigned short)(wp2 & 0xFFFF);
        wtbl[f][1][di][16 + t] = (unsigned short)(wp2 >> 16);
    }

    // ---- stage 2 conv (MFMA, both images) ----
    f32x4 o2_[2][2][2];
    mconv2(ev0, pv0, ev1, pv1, wtbl[f], q, n15, o2_);

    float* feat0 = mlp2[0];
    float* feat1 = mlp2[1];

    // 4x4 mean pool straight from C-registers (both images)
#pragma unroll
    for (int rt = 0; rt < 2; ++rt)
#pragma unroll
        for (int ct = 0; ct < 2; ++ct) {
            float s0 = o2_[0][rt][ct][0] + o2_[0][rt][ct][1] + o2_[0][rt][ct][2] + o2_[0][rt][ct][3];
            float s1 = o2_[1][rt][ct][0] + o2_[1][rt][ct][1] + o2_[1][rt][ct][2] + o2_[1][rt][ct][3];
            s0 += __shfl_xor(s0, 1);  s1 += __shfl_xor(s1, 1);
            s0 += __shfl_xor(s0, 2);  s1 += __shfl_xor(s1, 2);
            int pr = rt ? (3 + q) : q;
            int pc = (ct ? 4 : 0) + (n15 >> 2);
            bool ok = ((n15 & 3) == 0)
                   && !(rt == 1 && q == 0)          // rows 12..15 dup of rt=0,q=3
                   && !(ct == 1 && n15 >= 12);      // junk cols 28..31
            if (ok) {
                feat0[f * 49 + pr * 7 + pc] = s0 * 0.0625f;
                feat1[f * 49 + pr * 7 + pc] = s1 * 0.0625f;
            }
        }
    __syncthreads();

    // ---- inline MLP: each thread handles BOTH images (shared weight loads) ----
    float* h1_0 = mlp2[0] + 392;  float* h2_0 = mlp2[0] + 512;
    float* h1_1 = mlp2[1] + 392;  float* h2_1 = mlp2[1] + 512;

    if (tid < 480) {
        int n = tid >> 2, h = tid & 3;
        const float4* wr = (const float4*)(W1 + n * 392);
        const float4* f0 = (const float4*)feat0;
        const float4* f1 = (const float4*)feat1;
        float a00 = 0.f, a01 = 0.f, a02 = 0.f, a03 = 0.f;
        float a10 = 0.f, a11 = 0.f, a12 = 0.f, a13 = 0.f;
        for (int k = h; k < 98; k += 4) {
            float4 w  = wr[k];
            float4 u0 = f0[k];
            float4 u1 = f1[k];
            a00 = fmaf(w.x, u0.x, a00);  a10 = fmaf(w.x, u1.x, a10);
            a01 = fmaf(w.y, u0.y, a01);  a11 = fmaf(w.y, u1.y, a11);
            a02 = fmaf(w.z, u0.z, a02);  a12 = fmaf(w.z, u1.z, a12);
            a03 = fmaf(w.w, u0.w, a03);  a13 = fmaf(w.w, u1.w, a13);
        }
        float acc0 = (a00 + a01) + (a02 + a03);
        float acc1 = (a10 + a11) + (a12 + a13);
        acc0 += __shfl_xor(acc0, 1);  acc1 += __shfl_xor(acc1, 1);
        acc0 += __shfl_xor(acc0, 2);  acc1 += __shfl_xor(acc1, 2);
        if (h == 0) {
            h1_0[n] = sigmoidf_(acc0 + b1[n]);
            h1_1[n] = sigmoidf_(acc1 + b1[n]);
        }
    }
    __syncthreads();

    if (tid < 336) {
        int n = tid >> 2, h = tid & 3;
        const float4* wr = (const float4*)(W2 + n * 120);
        const float4* v0 = (const float4*)h1_0;
        const float4* v1 = (const float4*)h1_1;
        float a00 = 0.f, a01 = 0.f, a02 = 0.f, a03 = 0.f;
        float a10 = 0.f, a11 = 0.f, a12 = 0.f, a13 = 0.f;
        for (int k = h; k < 30; k += 4) {
            float4 w  = wr[k];
            float4 u0 = v0[k];
            float4 u1 = v1[k];
            a00 = fmaf(w.x, u0.x, a00);  a10 = fmaf(w.x, u1.x, a10);
            a01 = fmaf(w.y, u0.y, a01);  a11 = fmaf(w.y, u1.y, a11);
            a02 = fmaf(w.z, u0.z, a02);  a12 = fmaf(w.z, u1.z, a12);
            a03 = fmaf(w.w, u0.w, a03);  a13 = fmaf(w.w, u1.w, a13);
        }
        float acc0 = (a00 + a01) + (a02 + a03);
        float acc1 = (a10 + a11) + (a12 + a13);
        acc0 += __shfl_xor(acc0, 1);  acc1 += __shfl_xor(acc1, 1);
        acc0 += __shfl_xor(acc0, 2);  acc1 += __shfl_xor(acc1, 2);
        if (h == 0) {
            h2_0[n] = sigmoidf_(acc0 + b2[n]);
            h2_1[n] = sigmoidf_(acc1 + b2[n]);
        }
    }
    __syncthreads();

    if (tid < 40) {
        int n = tid >> 2, qh = tid & 3;
        const float4* wr = (const float4*)(W3 + n * 84);
        const float4* v0 = (const float4*)h2_0;
        const float4* v1 = (const float4*)h2_1;
        float a00 = 0.f, a01 = 0.f, a02 = 0.f, a03 = 0.f;
        float a10 = 0.f, a11 = 0.f, a12 = 0.f, a13 = 0.f;
        for (int k = qh; k < 21; k += 4) {
            float4 w  = wr[k];
            float4 u0 = v0[k];
            float4 u1 = v1[k];
            a00 = fmaf(w.x, u0.x, a00);  a10 = fmaf(w.x, u1.x, a10);
            a01 = fmaf(w.y, u0.y, a01);  a11 = fmaf(w.y, u1.y, a11);
            a02 = fmaf(w.z, u0.z, a02);  a12 = fmaf(w.z, u1.z, a12);
            a03 = fmaf(w.w, u0.w, a03);  a13 = fmaf(w.w, u1.w, a13);
        }
        float acc0 = (a00 + a01) + (a02 + a03);
        float acc1 = (a10 + a11) + (a12 + a13);
        acc0 += __shfl_xor(acc0, 1);  acc1 += __shfl_xor(acc1, 1);
        acc0 += __shfl_xor(acc0, 2);  acc1 += __shfl_xor(acc1, 2);
        if (qh == 0) {
            out[(size_t)b0 * 10 + n]       = sigmoidf_(acc0 + b3[n]);
            out[(size_t)(b0 + 1) * 10 + n] = sigmoidf_(acc1 + b3[n]);
        }
    }
}

extern "C" void kernel_launch(void* const* d_in, const int* in_sizes, int n_in,
                              void* d_out, int out_size, void* d_ws, size_t ws_size,
                              hipStream_t stream) {
    const float* x  = (const float*)d_in[0];
    const float* sw = (const float*)d_in[1];
    const float* sa = (const float*)d_in[2];
    const float* W1 = (const float*)d_in[3];
    const float* b1 = (const float*)d_in[4];
    const float* W2 = (const float*)d_in[5];
    const float* b2 = (const float*)d_in[6];
    const float* W3 = (const float*)d_in[7];
    const float* b3 = (const float*)d_in[8];
    float* out = (float*)d_out;

    smorph_net_kernel<<<NBLK, 512, 0, stream>>>(x, sw, sa, W1, b1, W2, b2, W3, b3, out);
}